// Round 14
// baseline (303.797 us; speedup 1.0000x reference)
//
#include <hip/hip_runtime.h>
#include <hip/hip_bf16.h>
#include <stdint.h>

typedef uint16_t u16;
typedef __attribute__((ext_vector_type(8))) short bf16x8;
typedef __attribute__((ext_vector_type(4))) float f32x4;

#define DEVI static __device__ __forceinline__
#define GLOAD_LDS(gptr, lptr) \
  __builtin_amdgcn_global_load_lds((const __attribute__((address_space(1))) void*)(gptr), \
                                   (__attribute__((address_space(3))) void*)(lptr), 16, 0, 0)

constexpr int Bc = 4, Sc = 1024, Hc = 1024, NHc = 16, HDc = 64;
constexpr int Mrows = Bc * Sc; // 4096

DEVI u16 f2bf(float f) {
  uint32_t u = __builtin_bit_cast(uint32_t, f);
  u += 0x7FFFu + ((u >> 16) & 1u);
  return (u16)(u >> 16);
}
DEVI float bf2f(u16 x) { return __builtin_bit_cast(float, (uint32_t)x << 16); }

DEVI f32x4 mfma16(bf16x8 a, bf16x8 b, f32x4 c) {
  return __builtin_amdgcn_mfma_f32_16x16x32_bf16(a, b, c, 0, 0, 0);
}

// ---------------- batched f32 -> bf16 conversion ----------------
struct CV { const float* in[6]; u16* out[6]; };

__global__ __launch_bounds__(256) void cvtN_kernel(CV a, int n8) {
  int z = blockIdx.z;
  int i = blockIdx.x * 256 + threadIdx.x;
  if (i >= n8) return;
  const f32x4* p = (const f32x4*)(a.in[z] + (size_t)i * 8);
  f32x4 x = p[0], y = p[1];
  union { bf16x8 v; u16 s[8]; } r;
#pragma unroll
  for (int j = 0; j < 4; ++j) { r.s[j] = f2bf(x[j]); r.s[4 + j] = f2bf(y[j]); }
  *(bf16x8*)(a.out[z] + (size_t)i * 8) = r.v;
}

// ---------------- mask int32 -> bitmask ----------------
__global__ __launch_bounds__(256) void maskpack_kernel(const int* __restrict__ mask,
                                                       uint32_t* __restrict__ out) {
  int i = blockIdx.x * 256 + threadIdx.x;
  const int4* p = (const int4*)(mask + (size_t)i * 32);
  uint32_t r = 0;
#pragma unroll
  for (int j = 0; j < 8; ++j) {
    int4 v = p[j];
    uint32_t nib = (v.x ? 1u : 0u) | (v.y ? 2u : 0u) | (v.z ? 4u : 0u) | (v.w ? 8u : 0u);
    r |= nib << (j * 4);
  }
  out[i] = r;
}

// ---------------- fused 5-way projection GEMM ----------------
struct P5 { const u16* A[5]; const u16* W[5]; const float* b[5]; u16* o[5]; };

__global__ __launch_bounds__(256) void proj5_kernel(P5 args) {
  constexpr int K = 1024, BK = 32;
  __shared__ u16 As[128 * BK];
  __shared__ u16 Bs[128 * BK];
  const int z = blockIdx.z;
  const u16* __restrict__ A = args.A[z];
  const u16* __restrict__ Bw = args.W[z];
  const float* __restrict__ bias = args.b[z];
  u16* __restrict__ Cout = args.o[z];
  const int t = threadIdx.x;
  const int w = t >> 6, l = t & 63;
  const int lr = l & 15, lh = l >> 4;
  const int m0 = blockIdx.y * 128, n0 = blockIdx.x * 128;
  const int wr = w >> 1, wc = w & 1;
  f32x4 acc[4][4] = {};

  const int row_s = t >> 2, k8 = (t & 3) << 3;
  const u16* ga = A + (size_t)(m0 + row_s) * K + k8;
  const u16* gb = Bw + (size_t)(n0 + row_s) * K + k8;

  for (int kt = 0; kt < K; kt += BK) {
    GLOAD_LDS(ga + kt, As + t * 8);
    GLOAD_LDS(ga + (size_t)64 * K + kt, As + 2048 + t * 8);
    GLOAD_LDS(gb + kt, Bs + t * 8);
    GLOAD_LDS(gb + (size_t)64 * K + kt, Bs + 2048 + t * 8);
    __syncthreads();
    bf16x8 af[4], bfr[4];
#pragma unroll
    for (int mi = 0; mi < 4; ++mi)
      af[mi] = *(const bf16x8*)(As + (wr * 64 + mi * 16 + lr) * BK + lh * 8);
#pragma unroll
    for (int ni = 0; ni < 4; ++ni)
      bfr[ni] = *(const bf16x8*)(Bs + (wc * 64 + ni * 16 + lr) * BK + lh * 8);
#pragma unroll
    for (int mi = 0; mi < 4; ++mi)
#pragma unroll
      for (int ni = 0; ni < 4; ++ni)
        acc[mi][ni] = mfma16(af[mi], bfr[ni], acc[mi][ni]);
    __syncthreads();
  }

#pragma unroll
  for (int mi = 0; mi < 4; ++mi) {
#pragma unroll
    for (int ni = 0; ni < 4; ++ni) {
      int col = n0 + wc * 64 + ni * 16 + lr;
      float bc = bias[col];
      int hcol = col >> 6, dcol = col & 63;
      int rbase = m0 + wr * 64 + mi * 16 + lh * 4;
      int bb = rbase >> 10, sb = rbase & 1023;
      if (z == 4) {
        ushort4 pk;
        pk.x = f2bf(acc[mi][ni][0] + bc);
        pk.y = f2bf(acc[mi][ni][1] + bc);
        pk.z = f2bf(acc[mi][ni][2] + bc);
        pk.w = f2bf(acc[mi][ni][3] + bc);
        *(ushort4*)&Cout[((size_t)(bb * NHc + hcol) * HDc + dcol) * Sc + sb] = pk;
      } else {
#pragma unroll
        for (int r = 0; r < 4; ++r)
          Cout[((size_t)(bb * NHc + hcol) * Sc + (sb + r)) * HDc + dcol] =
              f2bf(acc[mi][ni][r] + bc);
      }
    }
  }
}

// ---------------- output projection GEMM (f32 out, [M,N]) ----------------
__global__ __launch_bounds__(256) void gemmo_kernel(const u16* __restrict__ A,
                                                    const u16* __restrict__ Bw,
                                                    const float* __restrict__ bias,
                                                    float* __restrict__ Cout) {
  constexpr int K = 1024, N = 1024, BK = 32;
  __shared__ u16 As[128 * BK];
  __shared__ u16 Bs[128 * BK];
  const int t = threadIdx.x;
  const int w = t >> 6, l = t & 63;
  const int lr = l & 15, lh = l >> 4;
  const int m0 = blockIdx.y * 128, n0 = blockIdx.x * 128;
  const int wr = w >> 1, wc = w & 1;
  f32x4 acc[4][4] = {};

  const int row_s = t >> 2, k8 = (t & 3) << 3;
  const u16* ga = A + (size_t)(m0 + row_s) * K + k8;
  const u16* gb = Bw + (size_t)(n0 + row_s) * K + k8;

  for (int kt = 0; kt < K; kt += BK) {
    GLOAD_LDS(ga + kt, As + t * 8);
    GLOAD_LDS(ga + (size_t)64 * K + kt, As + 2048 + t * 8);
    GLOAD_LDS(gb + kt, Bs + t * 8);
    GLOAD_LDS(gb + (size_t)64 * K + kt, Bs + 2048 + t * 8);
    __syncthreads();
    bf16x8 af[4], bfr[4];
#pragma unroll
    for (int mi = 0; mi < 4; ++mi)
      af[mi] = *(const bf16x8*)(As + (wr * 64 + mi * 16 + lr) * BK + lh * 8);
#pragma unroll
    for (int ni = 0; ni < 4; ++ni)
      bfr[ni] = *(const bf16x8*)(Bs + (wc * 64 + ni * 16 + lr) * BK + lh * 8);
#pragma unroll
    for (int mi = 0; mi < 4; ++mi)
#pragma unroll
      for (int ni = 0; ni < 4; ++ni)
        acc[mi][ni] = mfma16(af[mi], bfr[ni], acc[mi][ni]);
    __syncthreads();
  }

#pragma unroll
  for (int mi = 0; mi < 4; ++mi) {
#pragma unroll
    for (int ni = 0; ni < 4; ++ni) {
      int col = n0 + wc * 64 + ni * 16 + lr;
      float bc = bias[col];
#pragma unroll
      for (int r = 0; r < 4; ++r) {
        int rowg = m0 + wr * 64 + mi * 16 + lh * 4 + r;
        Cout[(size_t)rowg * N + col] = acc[mi][ni][r] + bc;
      }
    }
  }
}

// ---------------- fused attention v6: 64-row q-tile, 512 threads ------------
// 1024 blocks (16 q-tiles x 64 bh), 8 waves, 128 KB dynamic LDS.
// Energy: wave w owns k-window [w*128,+128) (8 iters); each K/Ks frag feeds
// FOUR q-groups (rows q0+g*16+lr) -> 16 MFMA per 4 K-loads.
// E tile bf16 [64][1024], swizzle: phys granule = (k>>3) ^ (row&7).
// Softmax: wave w owns rows w*8..w*8+7, full row in-wave (exact), coalesced
// cached f32 P stores inline.
// PV: wave w -> row-group rg=w>>1 (16 rows), d-half dh=w&1 (32 cols, 2 tiles);
// A-frags shared across both d-tiles.
__global__ __launch_bounds__(512, 2) void attn6_kernel(const u16* __restrict__ Qh,
                                                       const u16* __restrict__ Kh,
                                                       const u16* __restrict__ Qsh,
                                                       const u16* __restrict__ Ksh,
                                                       const u16* __restrict__ Vth,
                                                       const uint32_t* __restrict__ mbits,
                                                       float* __restrict__ Pout,
                                                       u16* __restrict__ ctx) {
  extern __shared__ __align__(16) u16 E[]; // 64 * 1024 bf16 = 128 KB
  const int t = threadIdx.x, w = t >> 6, l = t & 63;
  const int lr = l & 15, lh = l >> 4;
  // XCD-aware remap: 16 q-tiles of one head stay on one XCD
  int lid = blockIdx.y * 16 + blockIdx.x;
  int xcd = lid & 7, j = lid >> 3;
  int bh = xcd * 8 + (j >> 4);
  int q0 = (j & 15) << 6;
  const int b = bh >> 4, h = bh & 15;
  const size_t hoff = (size_t)bh * Sc * HDc;

  // ---- Q fragments, 4 groups ----
  bf16x8 qf[4][2], sf[4][2];
#pragma unroll
  for (int g = 0; g < 4; ++g) {
    const u16* Qp = Qh + hoff + (size_t)(q0 + g * 16 + lr) * HDc + lh * 8;
    const u16* Qsp = Qsh + hoff + (size_t)(q0 + g * 16 + lr) * HDc + lh * 8;
    qf[g][0] = *(const bf16x8*)Qp;  qf[g][1] = *(const bf16x8*)(Qp + 32);
    sf[g][0] = *(const bf16x8*)Qsp; sf[g][1] = *(const bf16x8*)(Qsp + 32);
  }

  // ---- mask: per group 4 dwords for window [w*128,(w+1)*128) ----
  uint32_t mw[4][4];
#pragma unroll
  for (int g = 0; g < 4; ++g) {
    const uint32_t* mrow = mbits + ((size_t)b * Sc + q0 + g * 16 + lr) * 32 + w * 4;
    *(uint4*)&mw[g][0] = *(const uint4*)mrow;
  }

  // ---- energy: 8 iters, depth-2 K prefetch; each frag feeds 4 groups ----
  const u16* Kbase = Kh + hoff + (size_t)((w << 7) + lr) * HDc + lh * 8;
  const u16* Ksbase = Ksh + hoff + (size_t)((w << 7) + lr) * HDc + lh * 8;
  bf16x8 ka[2], kb[2], sa[2], sb[2];
#define LOADK(slot, it) do { \
    const u16* Kp_ = Kbase + (it) * (16 * HDc); \
    const u16* Sp_ = Ksbase + (it) * (16 * HDc); \
    ka[slot] = *(const bf16x8*)Kp_;  kb[slot] = *(const bf16x8*)(Kp_ + 32); \
    sa[slot] = *(const bf16x8*)Sp_;  sb[slot] = *(const bf16x8*)(Sp_ + 32); } while (0)

  LOADK(0, 0); LOADK(1, 1);

#pragma unroll
  for (int kt = 0; kt < 8; ++kt) {
    const int s = kt & 1;
    const int kbase = (w << 7) + (kt << 4) + (lh << 2);
    const int sphys = ((((kbase >> 3) ^ (lr & 7)) << 3) | (kbase & 7));
    const int sh = ((kt & 1) << 4) + (lh << 2);
#pragma unroll
    for (int g = 0; g < 4; ++g) {
      f32x4 e = {}, es = {};
      e = mfma16(ka[s], qf[g][0], e);
      e = mfma16(kb[s], qf[g][1], e);
      es = mfma16(sa[s], sf[g][0], es);
      es = mfma16(sb[s], sf[g][1], es);
      uint32_t md = mw[g][kt >> 1];
      ushort4 wb;
      wb.x = f2bf(((md >> (sh + 0)) & 1u ? es[0] : e[0]) * 0.125f);
      wb.y = f2bf(((md >> (sh + 1)) & 1u ? es[1] : e[1]) * 0.125f);
      wb.z = f2bf(((md >> (sh + 2)) & 1u ? es[2] : e[2]) * 0.125f);
      wb.w = f2bf(((md >> (sh + 3)) & 1u ? es[3] : e[3]) * 0.125f);
      const int row = g * 16 + lr;
      *(ushort4*)&E[(row << 10) + sphys] = wb;
    }
    if (kt + 2 < 8) LOADK(s, kt + 2);
  }
#undef LOADK
  __syncthreads();

  // ---- softmax: wave w owns rows w*8..w*8+7 (full row in-wave, exact) ----
  float* Pb = Pout + ((size_t)bh * Sc + q0) * Sc;
#pragma unroll
  for (int r8 = 0; r8 < 8; ++r8) {
    const int row = (w << 3) + r8;
    const int sw = row & 7;
    float v[4][4];
#pragma unroll
    for (int jj = 0; jj < 4; ++jj) {
      int k = (jj << 8) + (l << 2);
      ushort4 raw = *(const ushort4*)&E[(row << 10) + ((((k >> 3) ^ sw) << 3) | (k & 7))];
      v[jj][0] = bf2f(raw.x); v[jj][1] = bf2f(raw.y);
      v[jj][2] = bf2f(raw.z); v[jj][3] = bf2f(raw.w);
    }
    float m = -1e30f;
#pragma unroll
    for (int jj = 0; jj < 4; ++jj)
      m = fmaxf(m, fmaxf(fmaxf(v[jj][0], v[jj][1]), fmaxf(v[jj][2], v[jj][3])));
#pragma unroll
    for (int off = 1; off < 64; off <<= 1) m = fmaxf(m, __shfl_xor(m, off));
    float sum = 0.f;
#pragma unroll
    for (int jj = 0; jj < 4; ++jj)
#pragma unroll
      for (int i = 0; i < 4; ++i) { float tt = __expf(v[jj][i] - m); v[jj][i] = tt; sum += tt; }
#pragma unroll
    for (int off = 1; off < 64; off <<= 1) sum += __shfl_xor(sum, off);
    const float inv = 1.f / sum;
#pragma unroll
    for (int jj = 0; jj < 4; ++jj) {
      int k = (jj << 8) + (l << 2);
      f32x4 pv = { v[jj][0] * inv, v[jj][1] * inv, v[jj][2] * inv, v[jj][3] * inv };
      *(f32x4*)(Pb + (size_t)row * Sc + k) = pv;   // cached, 1KB/wave-instr
      ushort4 wb;
      wb.x = f2bf(pv[0]); wb.y = f2bf(pv[1]); wb.z = f2bf(pv[2]); wb.w = f2bf(pv[3]);
      *(ushort4*)&E[(row << 10) + ((((k >> 3) ^ sw) << 3) | (k & 7))] = wb;
    }
  }

  // ---- V prefetch (depth-2) before the barrier ----
  const int rg = w >> 1, dh = w & 1;
  const u16* V0 = Vth + ((size_t)bh * HDc + dh * 32 + lr) * Sc + lh * 8;
  const u16* V1 = V0 + (size_t)16 * Sc;
  bf16x8 v00[2], v01[2], v10[2], v11[2];
#define LOADV(slot, it) do { \
    v00[slot] = *(const bf16x8*)(V0 + (it) * 64); \
    v01[slot] = *(const bf16x8*)(V0 + (it) * 64 + 32); \
    v10[slot] = *(const bf16x8*)(V1 + (it) * 64); \
    v11[slot] = *(const bf16x8*)(V1 + (it) * 64 + 32); } while (0)
  LOADV(0, 0); LOADV(1, 1);

  __syncthreads();

  // ---- PV: rows rg*16..+16, d-cols dh*32..+32 (2 tiles, shared A-frags) ----
  const int arow = rg * 16 + lr;
  const int swp = arow & 7;
  f32x4 acc0a = {}, acc0b = {}, acc1a = {}, acc1b = {};
#pragma unroll
  for (int it = 0; it < 16; ++it) {
    const int s = it & 1;
    int ka16 = (it << 6) + (lh << 3);
    bf16x8 a0 = *(const bf16x8*)&E[(arow << 10) + (((ka16 >> 3) ^ swp) << 3)];
    bf16x8 a1 = *(const bf16x8*)&E[(arow << 10) + ((((ka16 + 32) >> 3) ^ swp) << 3)];
    acc0a = mfma16(a0, v00[s], acc0a);
    acc0b = mfma16(a1, v01[s], acc0b);
    acc1a = mfma16(a0, v10[s], acc1a);
    acc1b = mfma16(a1, v11[s], acc1b);
    if (it + 2 < 16) LOADV(s, it + 2);
  }
#undef LOADV
  f32x4 acc0 = acc0a + acc0b;
  f32x4 acc1 = acc1a + acc1b;
#pragma unroll
  for (int r = 0; r < 4; ++r) {
    int row = q0 + rg * 16 + (lh << 2) + r;
    size_t base = ((size_t)b * Sc + row) * Hc + (h << 6) + dh * 32;
    ctx[base + lr] = f2bf(acc0[r]);
    ctx[base + 16 + lr] = f2bf(acc1[r]);
  }
}

extern "C" void kernel_launch(void* const* d_in, const int* in_sizes, int n_in,
                              void* d_out, int out_size, void* d_ws, size_t ws_size,
                              hipStream_t stream) {
  const float* fin[5] = { (const float*)d_in[0], (const float*)d_in[1], (const float*)d_in[2],
                          (const float*)d_in[3], (const float*)d_in[4] };
  const int* mask = (const int*)d_in[5];
  const float* W[6] = { (const float*)d_in[6], (const float*)d_in[8], (const float*)d_in[10],
                        (const float*)d_in[12], (const float*)d_in[14], (const float*)d_in[16] };
  const float* bias[6] = { (const float*)d_in[7], (const float*)d_in[9], (const float*)d_in[11],
                           (const float*)d_in[13], (const float*)d_in[15], (const float*)d_in[17] };

  float* out_x = (float*)d_out;
  float* out_attn = out_x + (size_t)Bc * Sc * Hc;

  const size_t NE = (size_t)Bc * Sc * Hc; // 4M elems
  const size_t NW = (size_t)Hc * Hc;      // 1M elems
  u16* p = (u16*)d_ws;
  u16* xin[5]; for (int i = 0; i < 5; ++i) { xin[i] = p; p += NE; }
  u16* wbf[6]; for (int i = 0; i < 6; ++i) { wbf[i] = p; p += NW; }
  u16* Qh  = p; p += NE;
  u16* Kh  = p; p += NE;
  u16* Qsh = p; p += NE;
  u16* Ksh = p; p += NE;
  u16* Vth = p; p += NE;
  u16* ctx = p; p += NE;
  uint32_t* mbits = (uint32_t*)xin[0]; // reused after proj5

  // allow 128 KB dynamic LDS for attn6 (host-side attribute, capture-safe)
  hipFuncSetAttribute(reinterpret_cast<const void*>(attn6_kernel),
                      hipFuncAttributeMaxDynamicSharedMemorySize, 131072);

  {
    CV a{};
    for (int i = 0; i < 5; ++i) { a.in[i] = fin[i]; a.out[i] = xin[i]; }
    cvtN_kernel<<<dim3((int)(NE / 8 / 256), 1, 5), 256, 0, stream>>>(a, (int)(NE / 8));
  }
  {
    CV a{};
    for (int i = 0; i < 6; ++i) { a.in[i] = W[i]; a.out[i] = wbf[i]; }
    cvtN_kernel<<<dim3((int)(NW / 8 / 256), 1, 6), 256, 0, stream>>>(a, (int)(NW / 8));
  }

  P5 args;
  u16* projout[5] = { Qh, Kh, Qsh, Ksh, Vth };
  for (int i = 0; i < 5; ++i) { args.A[i] = xin[i]; args.W[i] = wbf[i]; args.b[i] = bias[i]; args.o[i] = projout[i]; }
  proj5_kernel<<<dim3(Hc / 128, Mrows / 128, 5), 256, 0, stream>>>(args);

  maskpack_kernel<<<(int)((size_t)Bc * Sc * Sc / 32 / 256), 256, 0, stream>>>(mask, mbits);

  attn6_kernel<<<dim3(Sc / 64, Bc * NHc), 512, 131072, stream>>>(Qh, Kh, Qsh, Ksh, Vth, mbits, out_attn, ctx);

  gemmo_kernel<<<dim3(Hc / 128, Mrows / 128), 256, 0, stream>>>(ctx, wbf[5], bias[5], out_x);
}

// Round 15
// 279.765 us; speedup vs baseline: 1.0859x; 1.0859x over previous
//
#include <hip/hip_runtime.h>
#include <hip/hip_bf16.h>
#include <stdint.h>

typedef uint16_t u16;
typedef __attribute__((ext_vector_type(8))) short bf16x8;
typedef __attribute__((ext_vector_type(4))) float f32x4;

#define DEVI static __device__ __forceinline__
#define GLOAD_LDS(gptr, lptr) \
  __builtin_amdgcn_global_load_lds((const __attribute__((address_space(1))) void*)(gptr), \
                                   (__attribute__((address_space(3))) void*)(lptr), 16, 0, 0)

constexpr int Bc = 4, Sc = 1024, Hc = 1024, NHc = 16, HDc = 64;
constexpr int Mrows = Bc * Sc; // 4096

DEVI u16 f2bf(float f) {
  uint32_t u = __builtin_bit_cast(uint32_t, f);
  u += 0x7FFFu + ((u >> 16) & 1u);
  return (u16)(u >> 16);
}
DEVI float bf2f(u16 x) { return __builtin_bit_cast(float, (uint32_t)x << 16); }

DEVI f32x4 mfma16(bf16x8 a, bf16x8 b, f32x4 c) {
  return __builtin_amdgcn_mfma_f32_16x16x32_bf16(a, b, c, 0, 0, 0);
}

// LDS-only barrier: does NOT drain global stores (vmcnt) like __syncthreads.
DEVI void softbar() {
  asm volatile("s_waitcnt lgkmcnt(0)" ::: "memory");
  __builtin_amdgcn_s_barrier();
  __builtin_amdgcn_sched_barrier(0);
}

// ---------------- batched f32 -> bf16 conversion ----------------
struct CV { const float* in[6]; u16* out[6]; };

__global__ __launch_bounds__(256) void cvtN_kernel(CV a, int n8) {
  int z = blockIdx.z;
  int i = blockIdx.x * 256 + threadIdx.x;
  if (i >= n8) return;
  const f32x4* p = (const f32x4*)(a.in[z] + (size_t)i * 8);
  f32x4 x = p[0], y = p[1];
  union { bf16x8 v; u16 s[8]; } r;
#pragma unroll
  for (int j = 0; j < 4; ++j) { r.s[j] = f2bf(x[j]); r.s[4 + j] = f2bf(y[j]); }
  *(bf16x8*)(a.out[z] + (size_t)i * 8) = r.v;
}

// ---------------- mask int32 -> bitmask ----------------
__global__ __launch_bounds__(256) void maskpack_kernel(const int* __restrict__ mask,
                                                       uint32_t* __restrict__ out) {
  int i = blockIdx.x * 256 + threadIdx.x;
  const int4* p = (const int4*)(mask + (size_t)i * 32);
  uint32_t r = 0;
#pragma unroll
  for (int j = 0; j < 8; ++j) {
    int4 v = p[j];
    uint32_t nib = (v.x ? 1u : 0u) | (v.y ? 2u : 0u) | (v.z ? 4u : 0u) | (v.w ? 8u : 0u);
    r |= nib << (j * 4);
  }
  out[i] = r;
}

// ---------------- fused 5-way projection GEMM ----------------
struct P5 { const u16* A[5]; const u16* W[5]; const float* b[5]; u16* o[5]; };

__global__ __launch_bounds__(256) void proj5_kernel(P5 args) {
  constexpr int K = 1024, BK = 32;
  __shared__ u16 As[128 * BK];
  __shared__ u16 Bs[128 * BK];
  const int z = blockIdx.z;
  const u16* __restrict__ A = args.A[z];
  const u16* __restrict__ Bw = args.W[z];
  const float* __restrict__ bias = args.b[z];
  u16* __restrict__ Cout = args.o[z];
  const int t = threadIdx.x;
  const int w = t >> 6, l = t & 63;
  const int lr = l & 15, lh = l >> 4;
  const int m0 = blockIdx.y * 128, n0 = blockIdx.x * 128;
  const int wr = w >> 1, wc = w & 1;
  f32x4 acc[4][4] = {};

  const int row_s = t >> 2, k8 = (t & 3) << 3;
  const u16* ga = A + (size_t)(m0 + row_s) * K + k8;
  const u16* gb = Bw + (size_t)(n0 + row_s) * K + k8;

  for (int kt = 0; kt < K; kt += BK) {
    GLOAD_LDS(ga + kt, As + t * 8);
    GLOAD_LDS(ga + (size_t)64 * K + kt, As + 2048 + t * 8);
    GLOAD_LDS(gb + kt, Bs + t * 8);
    GLOAD_LDS(gb + (size_t)64 * K + kt, Bs + 2048 + t * 8);
    __syncthreads();
    bf16x8 af[4], bfr[4];
#pragma unroll
    for (int mi = 0; mi < 4; ++mi)
      af[mi] = *(const bf16x8*)(As + (wr * 64 + mi * 16 + lr) * BK + lh * 8);
#pragma unroll
    for (int ni = 0; ni < 4; ++ni)
      bfr[ni] = *(const bf16x8*)(Bs + (wc * 64 + ni * 16 + lr) * BK + lh * 8);
#pragma unroll
    for (int mi = 0; mi < 4; ++mi)
#pragma unroll
      for (int ni = 0; ni < 4; ++ni)
        acc[mi][ni] = mfma16(af[mi], bfr[ni], acc[mi][ni]);
    __syncthreads();
  }

#pragma unroll
  for (int mi = 0; mi < 4; ++mi) {
#pragma unroll
    for (int ni = 0; ni < 4; ++ni) {
      int col = n0 + wc * 64 + ni * 16 + lr;
      float bc = bias[col];
      int hcol = col >> 6, dcol = col & 63;
      int rbase = m0 + wr * 64 + mi * 16 + lh * 4;
      int bb = rbase >> 10, sb = rbase & 1023;
      if (z == 4) {
        ushort4 pk;
        pk.x = f2bf(acc[mi][ni][0] + bc);
        pk.y = f2bf(acc[mi][ni][1] + bc);
        pk.z = f2bf(acc[mi][ni][2] + bc);
        pk.w = f2bf(acc[mi][ni][3] + bc);
        *(ushort4*)&Cout[((size_t)(bb * NHc + hcol) * HDc + dcol) * Sc + sb] = pk;
      } else {
#pragma unroll
        for (int r = 0; r < 4; ++r)
          Cout[((size_t)(bb * NHc + hcol) * Sc + (sb + r)) * HDc + dcol] =
              f2bf(acc[mi][ni][r] + bc);
      }
    }
  }
}

// ---------------- output projection GEMM (f32 out, [M,N]), 128x64 tile ------
__global__ __launch_bounds__(256) void gemmo_kernel(const u16* __restrict__ A,
                                                    const u16* __restrict__ Bw,
                                                    const float* __restrict__ bias,
                                                    float* __restrict__ Cout) {
  constexpr int K = 1024, N = 1024, BK = 32;
  __shared__ u16 As[128 * BK];
  __shared__ u16 Bs[64 * BK];
  const int t = threadIdx.x;
  const int w = t >> 6, l = t & 63;
  const int lr = l & 15, lh = l >> 4;
  const int m0 = blockIdx.y * 128, n0 = blockIdx.x * 64;
  const int wr = w >> 1, wc = w & 1;
  f32x4 acc[4][2] = {};

  const int row_s = t >> 2, k8 = (t & 3) << 3;
  const u16* ga = A + (size_t)(m0 + row_s) * K + k8;
  const u16* gb = Bw + (size_t)(n0 + row_s) * K + k8;

  for (int kt = 0; kt < K; kt += BK) {
    GLOAD_LDS(ga + kt, As + t * 8);
    GLOAD_LDS(ga + (size_t)64 * K + kt, As + 2048 + t * 8);
    GLOAD_LDS(gb + kt, Bs + t * 8);
    __syncthreads();
    bf16x8 af[4], bfr[2];
#pragma unroll
    for (int mi = 0; mi < 4; ++mi)
      af[mi] = *(const bf16x8*)(As + (wr * 64 + mi * 16 + lr) * BK + lh * 8);
#pragma unroll
    for (int ni = 0; ni < 2; ++ni)
      bfr[ni] = *(const bf16x8*)(Bs + (wc * 32 + ni * 16 + lr) * BK + lh * 8);
#pragma unroll
    for (int mi = 0; mi < 4; ++mi)
#pragma unroll
      for (int ni = 0; ni < 2; ++ni)
        acc[mi][ni] = mfma16(af[mi], bfr[ni], acc[mi][ni]);
    __syncthreads();
  }

#pragma unroll
  for (int mi = 0; mi < 4; ++mi) {
#pragma unroll
    for (int ni = 0; ni < 2; ++ni) {
      int col = n0 + wc * 32 + ni * 16 + lr;
      float bc = bias[col];
#pragma unroll
      for (int r = 0; r < 4; ++r) {
        int rowg = m0 + wr * 64 + mi * 16 + lh * 4 + r;
        Cout[(size_t)rowg * N + col] = acc[mi][ni][r] + bc;
      }
    }
  }
}

// ---------------- fused attention v7: attn5 + non-draining barriers ---------
// 2048 blocks (32 q-tiles x 64 bh). Two q-row groups per block.
// Same structure as attn5 (R13, best) plus:
//  - softbar(): lgkmcnt-only barriers; P stores stay in flight through PV.
//  - ALL V fragments preloaded to registers BEFORE the P stores (FIFO vmcnt:
//    waits for older V loads never drain younger stores); PV has no vmem.
__global__ __launch_bounds__(256, 2) void attn7_kernel(const u16* __restrict__ Qh,
                                                       const u16* __restrict__ Kh,
                                                       const u16* __restrict__ Qsh,
                                                       const u16* __restrict__ Ksh,
                                                       const u16* __restrict__ Vth,
                                                       const uint32_t* __restrict__ mbits,
                                                       float* __restrict__ Pout,
                                                       u16* __restrict__ ctx) {
  __shared__ __align__(16) u16 E[32 * 1024]; // 64 KB bf16
  const int t = threadIdx.x, w = t >> 6, l = t & 63;
  const int lr = l & 15, lh = l >> 4;
  int lid = blockIdx.y * 32 + blockIdx.x;
  int xcd = lid & 7, j = lid >> 3;
  int bh = xcd * 8 + (j >> 5);
  int q0 = (j & 31) << 5;
  const int b = bh >> 4, h = bh & 15;
  const size_t hoff = (size_t)bh * Sc * HDc;

  // ---- Q fragments, both groups ----
  const u16* QpA = Qh + hoff + (size_t)(q0 + lr) * HDc + lh * 8;
  const u16* QspA = Qsh + hoff + (size_t)(q0 + lr) * HDc + lh * 8;
  bf16x8 qfA0 = *(const bf16x8*)QpA, qfA1 = *(const bf16x8*)(QpA + 32);
  bf16x8 sfA0 = *(const bf16x8*)QspA, sfA1 = *(const bf16x8*)(QspA + 32);
  bf16x8 qfB0 = *(const bf16x8*)(QpA + 16 * HDc), qfB1 = *(const bf16x8*)(QpA + 16 * HDc + 32);
  bf16x8 sfB0 = *(const bf16x8*)(QspA + 16 * HDc), sfB1 = *(const bf16x8*)(QspA + 16 * HDc + 32);

  // ---- mask words ----
  uint32_t mwA[8], mwB[8];
  {
    const uint32_t* mA = mbits + ((size_t)b * Sc + q0 + lr) * 32 + w * 8;
    *(uint4*)&mwA[0] = *(const uint4*)mA;
    *(uint4*)&mwA[4] = *(const uint4*)(mA + 4);
    const uint32_t* mB = mA + 16 * 32;
    *(uint4*)&mwB[0] = *(const uint4*)mB;
    *(uint4*)&mwB[4] = *(const uint4*)(mB + 4);
  }

  // ---- energy: wave w covers k in [w*256,(w+1)*256), depth-2 K prefetch ----
  const u16* Kbase = Kh + hoff + (size_t)((w << 8) + lr) * HDc + lh * 8;
  const u16* Ksbase = Ksh + hoff + (size_t)((w << 8) + lr) * HDc + lh * 8;

  bf16x8 ka[2], kb[2], sa[2], sb[2];
#define LOADK(slot, it) do { \
    const u16* Kp_ = Kbase + (it) * (16 * HDc); \
    const u16* Sp_ = Ksbase + (it) * (16 * HDc); \
    ka[slot] = *(const bf16x8*)Kp_;  kb[slot] = *(const bf16x8*)(Kp_ + 32); \
    sa[slot] = *(const bf16x8*)Sp_;  sb[slot] = *(const bf16x8*)(Sp_ + 32); } while (0)

  LOADK(0, 0); LOADK(1, 1);

#pragma unroll
  for (int kt = 0; kt < 16; ++kt) {
    const int s = kt & 1;
    f32x4 eA = {}, esA = {}, eB = {}, esB = {};
    eA = mfma16(ka[s], qfA0, eA);
    eA = mfma16(kb[s], qfA1, eA);
    esA = mfma16(sa[s], sfA0, esA);
    esA = mfma16(sb[s], sfA1, esA);
    eB = mfma16(ka[s], qfB0, eB);
    eB = mfma16(kb[s], qfB1, eB);
    esB = mfma16(sa[s], sfB0, esB);
    esB = mfma16(sb[s], sfB1, esB);
    if (kt + 2 < 16) LOADK(s, kt + 2);
    const int sh = ((kt & 1) << 4) + (lh << 2);
    const int kb16 = (w << 8) + (kt << 4) + (lh << 2);
    const int sphys = ((((kb16 >> 3) ^ (lr & 7)) << 3) | (kb16 & 7));
    {
      uint32_t md = mwA[kt >> 1];
      ushort4 wb;
      wb.x = f2bf(((md >> (sh + 0)) & 1u ? esA[0] : eA[0]) * 0.125f);
      wb.y = f2bf(((md >> (sh + 1)) & 1u ? esA[1] : eA[1]) * 0.125f);
      wb.z = f2bf(((md >> (sh + 2)) & 1u ? esA[2] : eA[2]) * 0.125f);
      wb.w = f2bf(((md >> (sh + 3)) & 1u ? esA[3] : eA[3]) * 0.125f);
      *(ushort4*)&E[(lr << 10) + sphys] = wb;
    }
    {
      uint32_t md = mwB[kt >> 1];
      ushort4 wb;
      wb.x = f2bf(((md >> (sh + 0)) & 1u ? esB[0] : eB[0]) * 0.125f);
      wb.y = f2bf(((md >> (sh + 1)) & 1u ? esB[1] : eB[1]) * 0.125f);
      wb.z = f2bf(((md >> (sh + 2)) & 1u ? esB[2] : eB[2]) * 0.125f);
      wb.w = f2bf(((md >> (sh + 3)) & 1u ? esB[3] : eB[3]) * 0.125f);
      *(ushort4*)&E[((lr + 16) << 10) + sphys] = wb;
    }
  }
#undef LOADK
  softbar();

  // ---- V preload: ALL frags to registers BEFORE any P store is issued ----
  const u16* Vbp = Vth + ((size_t)bh * HDc + (w << 4) + lr) * Sc + lh * 8;
  bf16x8 vr0[16], vr1[16];
#pragma unroll
  for (int it = 0; it < 16; ++it) {
    vr0[it] = *(const bf16x8*)(Vbp + it * 64);
    vr1[it] = *(const bf16x8*)(Vbp + it * 64 + 32);
  }
  __builtin_amdgcn_sched_barrier(0); // keep V loads older than the P stores

  // ---- softmax: wave w owns rows w*8..w*8+7 (full row in-wave, exact) ----
  float* Pb = Pout + ((size_t)bh * Sc + q0) * Sc;
#pragma unroll
  for (int r8 = 0; r8 < 8; ++r8) {
    const int row = (w << 3) + r8;
    const int sw = row & 7;
    float v[4][4];
#pragma unroll
    for (int jj = 0; jj < 4; ++jj) {
      int k = (jj << 8) + (l << 2);
      ushort4 raw = *(const ushort4*)&E[(row << 10) + ((((k >> 3) ^ sw) << 3) | (k & 7))];
      v[jj][0] = bf2f(raw.x); v[jj][1] = bf2f(raw.y);
      v[jj][2] = bf2f(raw.z); v[jj][3] = bf2f(raw.w);
    }
    float m = -1e30f;
#pragma unroll
    for (int jj = 0; jj < 4; ++jj)
      m = fmaxf(m, fmaxf(fmaxf(v[jj][0], v[jj][1]), fmaxf(v[jj][2], v[jj][3])));
#pragma unroll
    for (int off = 1; off < 64; off <<= 1) m = fmaxf(m, __shfl_xor(m, off));
    float sum = 0.f;
#pragma unroll
    for (int jj = 0; jj < 4; ++jj)
#pragma unroll
      for (int i = 0; i < 4; ++i) { float tt = __expf(v[jj][i] - m); v[jj][i] = tt; sum += tt; }
#pragma unroll
    for (int off = 1; off < 64; off <<= 1) sum += __shfl_xor(sum, off);
    const float inv = 1.f / sum;
#pragma unroll
    for (int jj = 0; jj < 4; ++jj) {
      int k = (jj << 8) + (l << 2);
      f32x4 pv = { v[jj][0] * inv, v[jj][1] * inv, v[jj][2] * inv, v[jj][3] * inv };
      *(f32x4*)(Pb + (size_t)row * Sc + k) = pv;   // cached, 1KB/wave-instr
      ushort4 wb;
      wb.x = f2bf(pv[0]); wb.y = f2bf(pv[1]); wb.z = f2bf(pv[2]); wb.w = f2bf(pv[3]);
      *(ushort4*)&E[(row << 10) + ((((k >> 3) ^ sw) << 3) | (k & 7))] = wb;
    }
  }

  softbar(); // LDS-only: the P stores above keep draining during PV

  // ---- PV: wave w -> d-cols [w*16,+16); zero vmem in the loop ----
  const int swp = lr & 7;
  f32x4 accA0 = {}, accA1 = {}, accB0 = {}, accB1 = {};
#pragma unroll
  for (int it = 0; it < 16; ++it) {
    int ka16 = (it << 6) + (lh << 3);
    int offL = (((ka16 >> 3) ^ swp) << 3);
    int offH = ((((ka16 + 32) >> 3) ^ swp) << 3);
    bf16x8 aA0 = *(const bf16x8*)&E[(lr << 10) + offL];
    bf16x8 aA1 = *(const bf16x8*)&E[(lr << 10) + offH];
    bf16x8 aB0 = *(const bf16x8*)&E[((lr + 16) << 10) + offL];
    bf16x8 aB1 = *(const bf16x8*)&E[((lr + 16) << 10) + offH];
    accA0 = mfma16(aA0, vr0[it], accA0);
    accA1 = mfma16(aA1, vr1[it], accA1);
    accB0 = mfma16(aB0, vr0[it], accB0);
    accB1 = mfma16(aB1, vr1[it], accB1);
  }
  f32x4 accA = accA0 + accA1;
  f32x4 accB = accB0 + accB1;
#pragma unroll
  for (int r = 0; r < 4; ++r) {
    int rowA = q0 + (lh << 2) + r;
    ctx[((size_t)b * Sc + rowA) * Hc + (h << 6) + (w << 4) + lr] = f2bf(accA[r]);
    int rowB = rowA + 16;
    ctx[((size_t)b * Sc + rowB) * Hc + (h << 6) + (w << 4) + lr] = f2bf(accB[r]);
  }
}

extern "C" void kernel_launch(void* const* d_in, const int* in_sizes, int n_in,
                              void* d_out, int out_size, void* d_ws, size_t ws_size,
                              hipStream_t stream) {
  const float* fin[5] = { (const float*)d_in[0], (const float*)d_in[1], (const float*)d_in[2],
                          (const float*)d_in[3], (const float*)d_in[4] };
  const int* mask = (const int*)d_in[5];
  const float* W[6] = { (const float*)d_in[6], (const float*)d_in[8], (const float*)d_in[10],
                        (const float*)d_in[12], (const float*)d_in[14], (const float*)d_in[16] };
  const float* bias[6] = { (const float*)d_in[7], (const float*)d_in[9], (const float*)d_in[11],
                           (const float*)d_in[13], (const float*)d_in[15], (const float*)d_in[17] };

  float* out_x = (float*)d_out;
  float* out_attn = out_x + (size_t)Bc * Sc * Hc;

  const size_t NE = (size_t)Bc * Sc * Hc; // 4M elems
  const size_t NW = (size_t)Hc * Hc;      // 1M elems
  u16* p = (u16*)d_ws;
  u16* xin[5]; for (int i = 0; i < 5; ++i) { xin[i] = p; p += NE; }
  u16* wbf[6]; for (int i = 0; i < 6; ++i) { wbf[i] = p; p += NW; }
  u16* Qh  = p; p += NE;
  u16* Kh  = p; p += NE;
  u16* Qsh = p; p += NE;
  u16* Ksh = p; p += NE;
  u16* Vth = p; p += NE;
  u16* ctx = p; p += NE;
  uint32_t* mbits = (uint32_t*)xin[0]; // reused after proj5

  {
    CV a{};
    for (int i = 0; i < 5; ++i) { a.in[i] = fin[i]; a.out[i] = xin[i]; }
    cvtN_kernel<<<dim3((int)(NE / 8 / 256), 1, 5), 256, 0, stream>>>(a, (int)(NE / 8));
  }
  {
    CV a{};
    for (int i = 0; i < 6; ++i) { a.in[i] = W[i]; a.out[i] = wbf[i]; }
    cvtN_kernel<<<dim3((int)(NW / 8 / 256), 1, 6), 256, 0, stream>>>(a, (int)(NW / 8));
  }

  P5 args;
  u16* projout[5] = { Qh, Kh, Qsh, Ksh, Vth };
  for (int i = 0; i < 5; ++i) { args.A[i] = xin[i]; args.W[i] = wbf[i]; args.b[i] = bias[i]; args.o[i] = projout[i]; }
  proj5_kernel<<<dim3(Hc / 128, Mrows / 128, 5), 256, 0, stream>>>(args);

  maskpack_kernel<<<(int)((size_t)Bc * Sc * Sc / 32 / 256), 256, 0, stream>>>(mask, mbits);

  attn7_kernel<<<dim3(Sc / 32, Bc * NHc), 256, 0, stream>>>(Qh, Kh, Qsh, Ksh, Vth, mbits, out_attn, ctx);

  gemmo_kernel<<<dim3(Hc / 64, Mrows / 128), 256, 0, stream>>>(ctx, wbf[5], bias[5], out_x);
}

// Round 16
// 276.258 us; speedup vs baseline: 1.0997x; 1.0127x over previous
//
#include <hip/hip_runtime.h>
#include <hip/hip_bf16.h>
#include <stdint.h>

typedef uint16_t u16;
typedef __attribute__((ext_vector_type(8))) short bf16x8;
typedef __attribute__((ext_vector_type(4))) float f32x4;

#define DEVI static __device__ __forceinline__
#define GLOAD_LDS(gptr, lptr) \
  __builtin_amdgcn_global_load_lds((const __attribute__((address_space(1))) void*)(gptr), \
                                   (__attribute__((address_space(3))) void*)(lptr), 16, 0, 0)

constexpr int Bc = 4, Sc = 1024, Hc = 1024, NHc = 16, HDc = 64;
constexpr int Mrows = Bc * Sc; // 4096

DEVI u16 f2bf(float f) {
  uint32_t u = __builtin_bit_cast(uint32_t, f);
  u += 0x7FFFu + ((u >> 16) & 1u);
  return (u16)(u >> 16);
}
DEVI float bf2f(u16 x) { return __builtin_bit_cast(float, (uint32_t)x << 16); }

DEVI f32x4 mfma16(bf16x8 a, bf16x8 b, f32x4 c) {
  return __builtin_amdgcn_mfma_f32_16x16x32_bf16(a, b, c, 0, 0, 0);
}

// LDS-only barrier: does NOT drain global stores (vmcnt) like __syncthreads.
DEVI void softbar() {
  asm volatile("s_waitcnt lgkmcnt(0)" ::: "memory");
  __builtin_amdgcn_s_barrier();
  __builtin_amdgcn_sched_barrier(0);
}

// ---------------- batched f32 -> bf16 conversion ----------------
struct CV { const float* in[6]; u16* out[6]; };

__global__ __launch_bounds__(256) void cvtN_kernel(CV a, int n8) {
  int z = blockIdx.z;
  int i = blockIdx.x * 256 + threadIdx.x;
  if (i >= n8) return;
  const f32x4* p = (const f32x4*)(a.in[z] + (size_t)i * 8);
  f32x4 x = p[0], y = p[1];
  union { bf16x8 v; u16 s[8]; } r;
#pragma unroll
  for (int j = 0; j < 4; ++j) { r.s[j] = f2bf(x[j]); r.s[4 + j] = f2bf(y[j]); }
  *(bf16x8*)(a.out[z] + (size_t)i * 8) = r.v;
}

// ---------------- mask int32 -> bitmask ----------------
__global__ __launch_bounds__(256) void maskpack_kernel(const int* __restrict__ mask,
                                                       uint32_t* __restrict__ out) {
  int i = blockIdx.x * 256 + threadIdx.x;
  const int4* p = (const int4*)(mask + (size_t)i * 32);
  uint32_t r = 0;
#pragma unroll
  for (int j = 0; j < 8; ++j) {
    int4 v = p[j];
    uint32_t nib = (v.x ? 1u : 0u) | (v.y ? 2u : 0u) | (v.z ? 4u : 0u) | (v.w ? 8u : 0u);
    r |= nib << (j * 4);
  }
  out[i] = r;
}

// ---------------- fused 5-way projection GEMM ----------------
struct P5 { const u16* A[5]; const u16* W[5]; const float* b[5]; u16* o[5]; };

__global__ __launch_bounds__(256) void proj5_kernel(P5 args) {
  constexpr int K = 1024, BK = 32;
  __shared__ u16 As[128 * BK];
  __shared__ u16 Bs[128 * BK];
  const int z = blockIdx.z;
  const u16* __restrict__ A = args.A[z];
  const u16* __restrict__ Bw = args.W[z];
  const float* __restrict__ bias = args.b[z];
  u16* __restrict__ Cout = args.o[z];
  const int t = threadIdx.x;
  const int w = t >> 6, l = t & 63;
  const int lr = l & 15, lh = l >> 4;
  const int m0 = blockIdx.y * 128, n0 = blockIdx.x * 128;
  const int wr = w >> 1, wc = w & 1;
  f32x4 acc[4][4] = {};

  const int row_s = t >> 2, k8 = (t & 3) << 3;
  const u16* ga = A + (size_t)(m0 + row_s) * K + k8;
  const u16* gb = Bw + (size_t)(n0 + row_s) * K + k8;

  for (int kt = 0; kt < K; kt += BK) {
    GLOAD_LDS(ga + kt, As + t * 8);
    GLOAD_LDS(ga + (size_t)64 * K + kt, As + 2048 + t * 8);
    GLOAD_LDS(gb + kt, Bs + t * 8);
    GLOAD_LDS(gb + (size_t)64 * K + kt, Bs + 2048 + t * 8);
    __syncthreads();
    bf16x8 af[4], bfr[4];
#pragma unroll
    for (int mi = 0; mi < 4; ++mi)
      af[mi] = *(const bf16x8*)(As + (wr * 64 + mi * 16 + lr) * BK + lh * 8);
#pragma unroll
    for (int ni = 0; ni < 4; ++ni)
      bfr[ni] = *(const bf16x8*)(Bs + (wc * 64 + ni * 16 + lr) * BK + lh * 8);
#pragma unroll
    for (int mi = 0; mi < 4; ++mi)
#pragma unroll
      for (int ni = 0; ni < 4; ++ni)
        acc[mi][ni] = mfma16(af[mi], bfr[ni], acc[mi][ni]);
    __syncthreads();
  }

#pragma unroll
  for (int mi = 0; mi < 4; ++mi) {
#pragma unroll
    for (int ni = 0; ni < 4; ++ni) {
      int col = n0 + wc * 64 + ni * 16 + lr;
      float bc = bias[col];
      int hcol = col >> 6, dcol = col & 63;
      int rbase = m0 + wr * 64 + mi * 16 + lh * 4;
      int bb = rbase >> 10, sb = rbase & 1023;
      if (z == 4) {
        ushort4 pk;
        pk.x = f2bf(acc[mi][ni][0] + bc);
        pk.y = f2bf(acc[mi][ni][1] + bc);
        pk.z = f2bf(acc[mi][ni][2] + bc);
        pk.w = f2bf(acc[mi][ni][3] + bc);
        *(ushort4*)&Cout[((size_t)(bb * NHc + hcol) * HDc + dcol) * Sc + sb] = pk;
      } else {
#pragma unroll
        for (int r = 0; r < 4; ++r)
          Cout[((size_t)(bb * NHc + hcol) * Sc + (sb + r)) * HDc + dcol] =
              f2bf(acc[mi][ni][r] + bc);
      }
    }
  }
}

// ---------------- output projection GEMM (f32 out, [M,N]), 128x64 tile ------
__global__ __launch_bounds__(256) void gemmo_kernel(const u16* __restrict__ A,
                                                    const u16* __restrict__ Bw,
                                                    const float* __restrict__ bias,
                                                    float* __restrict__ Cout) {
  constexpr int K = 1024, N = 1024, BK = 32;
  __shared__ u16 As[128 * BK];
  __shared__ u16 Bs[64 * BK];
  const int t = threadIdx.x;
  const int w = t >> 6, l = t & 63;
  const int lr = l & 15, lh = l >> 4;
  const int m0 = blockIdx.y * 128, n0 = blockIdx.x * 64;
  const int wr = w >> 1, wc = w & 1;
  f32x4 acc[4][2] = {};

  const int row_s = t >> 2, k8 = (t & 3) << 3;
  const u16* ga = A + (size_t)(m0 + row_s) * K + k8;
  const u16* gb = Bw + (size_t)(n0 + row_s) * K + k8;

  for (int kt = 0; kt < K; kt += BK) {
    GLOAD_LDS(ga + kt, As + t * 8);
    GLOAD_LDS(ga + (size_t)64 * K + kt, As + 2048 + t * 8);
    GLOAD_LDS(gb + kt, Bs + t * 8);
    __syncthreads();
    bf16x8 af[4], bfr[2];
#pragma unroll
    for (int mi = 0; mi < 4; ++mi)
      af[mi] = *(const bf16x8*)(As + (wr * 64 + mi * 16 + lr) * BK + lh * 8);
#pragma unroll
    for (int ni = 0; ni < 2; ++ni)
      bfr[ni] = *(const bf16x8*)(Bs + (wc * 32 + ni * 16 + lr) * BK + lh * 8);
#pragma unroll
    for (int mi = 0; mi < 4; ++mi)
#pragma unroll
      for (int ni = 0; ni < 2; ++ni)
        acc[mi][ni] = mfma16(af[mi], bfr[ni], acc[mi][ni]);
    __syncthreads();
  }

#pragma unroll
  for (int mi = 0; mi < 4; ++mi) {
#pragma unroll
    for (int ni = 0; ni < 2; ++ni) {
      int col = n0 + wc * 32 + ni * 16 + lr;
      float bc = bias[col];
#pragma unroll
      for (int r = 0; r < 4; ++r) {
        int rowg = m0 + wr * 64 + mi * 16 + lh * 4 + r;
        Cout[(size_t)rowg * N + col] = acc[mi][ni][r] + bc;
      }
    }
  }
}

// ---------------- fused attention v8: attn7 + depth-4 K prefetch ------------
// 2048 blocks (32 q-tiles x 64 bh). Two q-row groups per block.
// LDS caps occupancy at 2 blocks/CU (2 waves/SIMD) -> latency hiding must be
// ILP. Energy-phase K/Ks loads are L2-latency-bound at depth-2 (~120cy
// exposed per iter); deepen rotating prefetch to DEPTH 4 (VGPRs are free at
// this occupancy). All else identical to attn7 (R15).
__global__ __launch_bounds__(256, 2) void attn8_kernel(const u16* __restrict__ Qh,
                                                       const u16* __restrict__ Kh,
                                                       const u16* __restrict__ Qsh,
                                                       const u16* __restrict__ Ksh,
                                                       const u16* __restrict__ Vth,
                                                       const uint32_t* __restrict__ mbits,
                                                       float* __restrict__ Pout,
                                                       u16* __restrict__ ctx) {
  __shared__ __align__(16) u16 E[32 * 1024]; // 64 KB bf16
  const int t = threadIdx.x, w = t >> 6, l = t & 63;
  const int lr = l & 15, lh = l >> 4;
  int lid = blockIdx.y * 32 + blockIdx.x;
  int xcd = lid & 7, j = lid >> 3;
  int bh = xcd * 8 + (j >> 5);
  int q0 = (j & 31) << 5;
  const int b = bh >> 4, h = bh & 15;
  const size_t hoff = (size_t)bh * Sc * HDc;

  // ---- Q fragments, both groups ----
  const u16* QpA = Qh + hoff + (size_t)(q0 + lr) * HDc + lh * 8;
  const u16* QspA = Qsh + hoff + (size_t)(q0 + lr) * HDc + lh * 8;
  bf16x8 qfA0 = *(const bf16x8*)QpA, qfA1 = *(const bf16x8*)(QpA + 32);
  bf16x8 sfA0 = *(const bf16x8*)QspA, sfA1 = *(const bf16x8*)(QspA + 32);
  bf16x8 qfB0 = *(const bf16x8*)(QpA + 16 * HDc), qfB1 = *(const bf16x8*)(QpA + 16 * HDc + 32);
  bf16x8 sfB0 = *(const bf16x8*)(QspA + 16 * HDc), sfB1 = *(const bf16x8*)(QspA + 16 * HDc + 32);

  // ---- mask words ----
  uint32_t mwA[8], mwB[8];
  {
    const uint32_t* mA = mbits + ((size_t)b * Sc + q0 + lr) * 32 + w * 8;
    *(uint4*)&mwA[0] = *(const uint4*)mA;
    *(uint4*)&mwA[4] = *(const uint4*)(mA + 4);
    const uint32_t* mB = mA + 16 * 32;
    *(uint4*)&mwB[0] = *(const uint4*)mB;
    *(uint4*)&mwB[4] = *(const uint4*)(mB + 4);
  }

  // ---- energy: wave w covers k in [w*256,(w+1)*256), DEPTH-4 K prefetch ----
  const u16* Kbase = Kh + hoff + (size_t)((w << 8) + lr) * HDc + lh * 8;
  const u16* Ksbase = Ksh + hoff + (size_t)((w << 8) + lr) * HDc + lh * 8;

  bf16x8 ka[4], kb[4], sa[4], sb[4];
#define LOADK(slot, it) do { \
    const u16* Kp_ = Kbase + (it) * (16 * HDc); \
    const u16* Sp_ = Ksbase + (it) * (16 * HDc); \
    ka[slot] = *(const bf16x8*)Kp_;  kb[slot] = *(const bf16x8*)(Kp_ + 32); \
    sa[slot] = *(const bf16x8*)Sp_;  sb[slot] = *(const bf16x8*)(Sp_ + 32); } while (0)

  LOADK(0, 0); LOADK(1, 1); LOADK(2, 2); LOADK(3, 3);

#pragma unroll
  for (int kt = 0; kt < 16; ++kt) {
    const int s = kt & 3;
    f32x4 eA = {}, esA = {}, eB = {}, esB = {};
    eA = mfma16(ka[s], qfA0, eA);
    eA = mfma16(kb[s], qfA1, eA);
    esA = mfma16(sa[s], sfA0, esA);
    esA = mfma16(sb[s], sfA1, esA);
    eB = mfma16(ka[s], qfB0, eB);
    eB = mfma16(kb[s], qfB1, eB);
    esB = mfma16(sa[s], sfB0, esB);
    esB = mfma16(sb[s], sfB1, esB);
    if (kt + 4 < 16) LOADK(s, kt + 4);
    const int sh = ((kt & 1) << 4) + (lh << 2);
    const int kb16 = (w << 8) + (kt << 4) + (lh << 2);
    const int sphys = ((((kb16 >> 3) ^ (lr & 7)) << 3) | (kb16 & 7));
    {
      uint32_t md = mwA[kt >> 1];
      ushort4 wb;
      wb.x = f2bf(((md >> (sh + 0)) & 1u ? esA[0] : eA[0]) * 0.125f);
      wb.y = f2bf(((md >> (sh + 1)) & 1u ? esA[1] : eA[1]) * 0.125f);
      wb.z = f2bf(((md >> (sh + 2)) & 1u ? esA[2] : eA[2]) * 0.125f);
      wb.w = f2bf(((md >> (sh + 3)) & 1u ? esA[3] : eA[3]) * 0.125f);
      *(ushort4*)&E[(lr << 10) + sphys] = wb;
    }
    {
      uint32_t md = mwB[kt >> 1];
      ushort4 wb;
      wb.x = f2bf(((md >> (sh + 0)) & 1u ? esB[0] : eB[0]) * 0.125f);
      wb.y = f2bf(((md >> (sh + 1)) & 1u ? esB[1] : eB[1]) * 0.125f);
      wb.z = f2bf(((md >> (sh + 2)) & 1u ? esB[2] : eB[2]) * 0.125f);
      wb.w = f2bf(((md >> (sh + 3)) & 1u ? esB[3] : eB[3]) * 0.125f);
      *(ushort4*)&E[((lr + 16) << 10) + sphys] = wb;
    }
  }
#undef LOADK
  softbar();

  // ---- V preload: ALL frags to registers BEFORE any P store is issued ----
  const u16* Vbp = Vth + ((size_t)bh * HDc + (w << 4) + lr) * Sc + lh * 8;
  bf16x8 vr0[16], vr1[16];
#pragma unroll
  for (int it = 0; it < 16; ++it) {
    vr0[it] = *(const bf16x8*)(Vbp + it * 64);
    vr1[it] = *(const bf16x8*)(Vbp + it * 64 + 32);
  }
  __builtin_amdgcn_sched_barrier(0); // keep V loads older than the P stores

  // ---- softmax: wave w owns rows w*8..w*8+7 (full row in-wave, exact) ----
  float* Pb = Pout + ((size_t)bh * Sc + q0) * Sc;
#pragma unroll
  for (int r8 = 0; r8 < 8; ++r8) {
    const int row = (w << 3) + r8;
    const int sw = row & 7;
    float v[4][4];
#pragma unroll
    for (int jj = 0; jj < 4; ++jj) {
      int k = (jj << 8) + (l << 2);
      ushort4 raw = *(const ushort4*)&E[(row << 10) + ((((k >> 3) ^ sw) << 3) | (k & 7))];
      v[jj][0] = bf2f(raw.x); v[jj][1] = bf2f(raw.y);
      v[jj][2] = bf2f(raw.z); v[jj][3] = bf2f(raw.w);
    }
    float m = -1e30f;
#pragma unroll
    for (int jj = 0; jj < 4; ++jj)
      m = fmaxf(m, fmaxf(fmaxf(v[jj][0], v[jj][1]), fmaxf(v[jj][2], v[jj][3])));
#pragma unroll
    for (int off = 1; off < 64; off <<= 1) m = fmaxf(m, __shfl_xor(m, off));
    float sum = 0.f;
#pragma unroll
    for (int jj = 0; jj < 4; ++jj)
#pragma unroll
      for (int i = 0; i < 4; ++i) { float tt = __expf(v[jj][i] - m); v[jj][i] = tt; sum += tt; }
#pragma unroll
    for (int off = 1; off < 64; off <<= 1) sum += __shfl_xor(sum, off);
    const float inv = 1.f / sum;
#pragma unroll
    for (int jj = 0; jj < 4; ++jj) {
      int k = (jj << 8) + (l << 2);
      f32x4 pv = { v[jj][0] * inv, v[jj][1] * inv, v[jj][2] * inv, v[jj][3] * inv };
      *(f32x4*)(Pb + (size_t)row * Sc + k) = pv;   // cached, 1KB/wave-instr
      ushort4 wb;
      wb.x = f2bf(pv[0]); wb.y = f2bf(pv[1]); wb.z = f2bf(pv[2]); wb.w = f2bf(pv[3]);
      *(ushort4*)&E[(row << 10) + ((((k >> 3) ^ sw) << 3) | (k & 7))] = wb;
    }
  }

  softbar(); // LDS-only: the P stores above keep draining during PV

  // ---- PV: wave w -> d-cols [w*16,+16); zero vmem in the loop ----
  const int swp = lr & 7;
  f32x4 accA0 = {}, accA1 = {}, accB0 = {}, accB1 = {};
#pragma unroll
  for (int it = 0; it < 16; ++it) {
    int ka16 = (it << 6) + (lh << 3);
    int offL = (((ka16 >> 3) ^ swp) << 3);
    int offH = ((((ka16 + 32) >> 3) ^ swp) << 3);
    bf16x8 aA0 = *(const bf16x8*)&E[(lr << 10) + offL];
    bf16x8 aA1 = *(const bf16x8*)&E[(lr << 10) + offH];
    bf16x8 aB0 = *(const bf16x8*)&E[((lr + 16) << 10) + offL];
    bf16x8 aB1 = *(const bf16x8*)&E[((lr + 16) << 10) + offH];
    accA0 = mfma16(aA0, vr0[it], accA0);
    accA1 = mfma16(aA1, vr1[it], accA1);
    accB0 = mfma16(aB0, vr0[it], accB0);
    accB1 = mfma16(aB1, vr1[it], accB1);
  }
  f32x4 accA = accA0 + accA1;
  f32x4 accB = accB0 + accB1;
#pragma unroll
  for (int r = 0; r < 4; ++r) {
    int rowA = q0 + (lh << 2) + r;
    ctx[((size_t)b * Sc + rowA) * Hc + (h << 6) + (w << 4) + lr] = f2bf(accA[r]);
    int rowB = rowA + 16;
    ctx[((size_t)b * Sc + rowB) * Hc + (h << 6) + (w << 4) + lr] = f2bf(accB[r]);
  }
}

extern "C" void kernel_launch(void* const* d_in, const int* in_sizes, int n_in,
                              void* d_out, int out_size, void* d_ws, size_t ws_size,
                              hipStream_t stream) {
  const float* fin[5] = { (const float*)d_in[0], (const float*)d_in[1], (const float*)d_in[2],
                          (const float*)d_in[3], (const float*)d_in[4] };
  const int* mask = (const int*)d_in[5];
  const float* W[6] = { (const float*)d_in[6], (const float*)d_in[8], (const float*)d_in[10],
                        (const float*)d_in[12], (const float*)d_in[14], (const float*)d_in[16] };
  const float* bias[6] = { (const float*)d_in[7], (const float*)d_in[9], (const float*)d_in[11],
                           (const float*)d_in[13], (const float*)d_in[15], (const float*)d_in[17] };

  float* out_x = (float*)d_out;
  float* out_attn = out_x + (size_t)Bc * Sc * Hc;

  const size_t NE = (size_t)Bc * Sc * Hc; // 4M elems
  const size_t NW = (size_t)Hc * Hc;      // 1M elems
  u16* p = (u16*)d_ws;
  u16* xin[5]; for (int i = 0; i < 5; ++i) { xin[i] = p; p += NE; }
  u16* wbf[6]; for (int i = 0; i < 6; ++i) { wbf[i] = p; p += NW; }
  u16* Qh  = p; p += NE;
  u16* Kh  = p; p += NE;
  u16* Qsh = p; p += NE;
  u16* Ksh = p; p += NE;
  u16* Vth = p; p += NE;
  u16* ctx = p; p += NE;
  uint32_t* mbits = (uint32_t*)xin[0]; // reused after proj5

  {
    CV a{};
    for (int i = 0; i < 5; ++i) { a.in[i] = fin[i]; a.out[i] = xin[i]; }
    cvtN_kernel<<<dim3((int)(NE / 8 / 256), 1, 5), 256, 0, stream>>>(a, (int)(NE / 8));
  }
  {
    CV a{};
    for (int i = 0; i < 6; ++i) { a.in[i] = W[i]; a.out[i] = wbf[i]; }
    cvtN_kernel<<<dim3((int)(NW / 8 / 256), 1, 6), 256, 0, stream>>>(a, (int)(NW / 8));
  }

  P5 args;
  u16* projout[5] = { Qh, Kh, Qsh, Ksh, Vth };
  for (int i = 0; i < 5; ++i) { args.A[i] = xin[i]; args.W[i] = wbf[i]; args.b[i] = bias[i]; args.o[i] = projout[i]; }
  proj5_kernel<<<dim3(Hc / 128, Mrows / 128, 5), 256, 0, stream>>>(args);

  maskpack_kernel<<<(int)((size_t)Bc * Sc * Sc / 32 / 256), 256, 0, stream>>>(mask, mbits);

  attn8_kernel<<<dim3(Sc / 32, Bc * NHc), 256, 0, stream>>>(Qh, Kh, Qsh, Ksh, Vth, mbits, out_attn, ctx);

  gemmo_kernel<<<dim3(Hc / 64, Mrows / 128), 256, 0, stream>>>(ctx, wbf[5], bias[5], out_x);
}

// Round 17
// 273.470 us; speedup vs baseline: 1.1109x; 1.0102x over previous
//
#include <hip/hip_runtime.h>
#include <hip/hip_bf16.h>
#include <stdint.h>

typedef uint16_t u16;
typedef __attribute__((ext_vector_type(8))) short bf16x8;
typedef __attribute__((ext_vector_type(4))) float f32x4;

#define DEVI static __device__ __forceinline__
#define GLOAD_LDS(gptr, lptr) \
  __builtin_amdgcn_global_load_lds((const __attribute__((address_space(1))) void*)(gptr), \
                                   (__attribute__((address_space(3))) void*)(lptr), 16, 0, 0)

constexpr int Bc = 4, Sc = 1024, Hc = 1024, NHc = 16, HDc = 64;
constexpr int Mrows = Bc * Sc; // 4096

DEVI u16 f2bf(float f) {
  uint32_t u = __builtin_bit_cast(uint32_t, f);
  u += 0x7FFFu + ((u >> 16) & 1u);
  return (u16)(u >> 16);
}
DEVI float bf2f(u16 x) { return __builtin_bit_cast(float, (uint32_t)x << 16); }

DEVI f32x4 mfma16(bf16x8 a, bf16x8 b, f32x4 c) {
  return __builtin_amdgcn_mfma_f32_16x16x32_bf16(a, b, c, 0, 0, 0);
}

// LDS-only barrier: does NOT drain global stores (vmcnt) like __syncthreads.
DEVI void softbar() {
  asm volatile("s_waitcnt lgkmcnt(0)" ::: "memory");
  __builtin_amdgcn_s_barrier();
  __builtin_amdgcn_sched_barrier(0);
}

// ---------------- batched f32 -> bf16 conversion ----------------
struct CV { const float* in[6]; u16* out[6]; };

__global__ __launch_bounds__(256) void cvtN_kernel(CV a, int n8) {
  int z = blockIdx.z;
  int i = blockIdx.x * 256 + threadIdx.x;
  if (i >= n8) return;
  const f32x4* p = (const f32x4*)(a.in[z] + (size_t)i * 8);
  f32x4 x = p[0], y = p[1];
  union { bf16x8 v; u16 s[8]; } r;
#pragma unroll
  for (int j = 0; j < 4; ++j) { r.s[j] = f2bf(x[j]); r.s[4 + j] = f2bf(y[j]); }
  *(bf16x8*)(a.out[z] + (size_t)i * 8) = r.v;
}

// ---------------- mask int32 -> bitmask ----------------
__global__ __launch_bounds__(256) void maskpack_kernel(const int* __restrict__ mask,
                                                       uint32_t* __restrict__ out) {
  int i = blockIdx.x * 256 + threadIdx.x;
  const int4* p = (const int4*)(mask + (size_t)i * 32);
  uint32_t r = 0;
#pragma unroll
  for (int j = 0; j < 8; ++j) {
    int4 v = p[j];
    uint32_t nib = (v.x ? 1u : 0u) | (v.y ? 2u : 0u) | (v.z ? 4u : 0u) | (v.w ? 8u : 0u);
    r |= nib << (j * 4);
  }
  out[i] = r;
}

// ---------------- fused 5-way projection GEMM, BK=64 + XOR swizzle ----------
// LDS [128][64] bf16 per matrix (32 KB total). 16B-granule swizzle:
//   LDS[row][gphys] = global[row][gphys ^ (row&7)]  (source pre-swizzled,
//   dest linear -> global_load_lds-compatible; reads use g = glog ^ (row&7)).
// ds_read_b128 banks: 8 distinct granules x 4 banks = all 32, 2 lanes/bank
// (free, m136). 32 MFMA per barrier pair (2x the BK=32 amortization).
struct P5 { const u16* A[5]; const u16* W[5]; const float* b[5]; u16* o[5]; };

__global__ __launch_bounds__(256) void proj5_kernel(P5 args) {
  constexpr int K = 1024, BK = 64;
  __shared__ u16 As[128 * BK];
  __shared__ u16 Bs[128 * BK];
  const int z = blockIdx.z;
  const u16* __restrict__ A = args.A[z];
  const u16* __restrict__ Bw = args.W[z];
  const float* __restrict__ bias = args.b[z];
  u16* __restrict__ Cout = args.o[z];
  const int t = threadIdx.x;
  const int w = t >> 6, l = t & 63;
  const int lr = l & 15, lh = l >> 4;
  const int m0 = blockIdx.y * 128, n0 = blockIdx.x * 128;
  const int wr = w >> 1, wc = w & 1;
  f32x4 acc[4][4] = {};

  for (int kt = 0; kt < K; kt += BK) {
#pragma unroll
    for (int i = 0; i < 4; ++i) {
      int c = i * 256 + t;
      int row = c >> 3, gp = c & 7;
      int gsrc = ((gp ^ (row & 7)) << 3);
      GLOAD_LDS(A + (size_t)(m0 + row) * K + kt + gsrc, As + (size_t)c * 8);
      GLOAD_LDS(Bw + (size_t)(n0 + row) * K + kt + gsrc, Bs + (size_t)c * 8);
    }
    __syncthreads();
#pragma unroll
    for (int kk = 0; kk < 2; ++kk) {
      bf16x8 af[4], bfr[4];
#pragma unroll
      for (int mi = 0; mi < 4; ++mi) {
        int row = wr * 64 + mi * 16 + lr;
        int g = (kk * 4 + lh) ^ (row & 7);
        af[mi] = *(const bf16x8*)(As + row * BK + g * 8);
      }
#pragma unroll
      for (int ni = 0; ni < 4; ++ni) {
        int row = wc * 64 + ni * 16 + lr;
        int g = (kk * 4 + lh) ^ (row & 7);
        bfr[ni] = *(const bf16x8*)(Bs + row * BK + g * 8);
      }
#pragma unroll
      for (int mi = 0; mi < 4; ++mi)
#pragma unroll
        for (int ni = 0; ni < 4; ++ni)
          acc[mi][ni] = mfma16(af[mi], bfr[ni], acc[mi][ni]);
    }
    __syncthreads();
  }

#pragma unroll
  for (int mi = 0; mi < 4; ++mi) {
#pragma unroll
    for (int ni = 0; ni < 4; ++ni) {
      int col = n0 + wc * 64 + ni * 16 + lr;
      float bc = bias[col];
      int hcol = col >> 6, dcol = col & 63;
      int rbase = m0 + wr * 64 + mi * 16 + lh * 4;
      int bb = rbase >> 10, sb = rbase & 1023;
      if (z == 4) {
        ushort4 pk;
        pk.x = f2bf(acc[mi][ni][0] + bc);
        pk.y = f2bf(acc[mi][ni][1] + bc);
        pk.z = f2bf(acc[mi][ni][2] + bc);
        pk.w = f2bf(acc[mi][ni][3] + bc);
        *(ushort4*)&Cout[((size_t)(bb * NHc + hcol) * HDc + dcol) * Sc + sb] = pk;
      } else {
#pragma unroll
        for (int r = 0; r < 4; ++r)
          Cout[((size_t)(bb * NHc + hcol) * Sc + (sb + r)) * HDc + dcol] =
              f2bf(acc[mi][ni][r] + bc);
      }
    }
  }
}

// ---------------- output projection GEMM (f32 out, [M,N]), 128x64 tile ------
__global__ __launch_bounds__(256) void gemmo_kernel(const u16* __restrict__ A,
                                                    const u16* __restrict__ Bw,
                                                    const float* __restrict__ bias,
                                                    float* __restrict__ Cout) {
  constexpr int K = 1024, N = 1024, BK = 32;
  __shared__ u16 As[128 * BK];
  __shared__ u16 Bs[64 * BK];
  const int t = threadIdx.x;
  const int w = t >> 6, l = t & 63;
  const int lr = l & 15, lh = l >> 4;
  const int m0 = blockIdx.y * 128, n0 = blockIdx.x * 64;
  const int wr = w >> 1, wc = w & 1;
  f32x4 acc[4][2] = {};

  const int row_s = t >> 2, k8 = (t & 3) << 3;
  const u16* ga = A + (size_t)(m0 + row_s) * K + k8;
  const u16* gb = Bw + (size_t)(n0 + row_s) * K + k8;

  for (int kt = 0; kt < K; kt += BK) {
    GLOAD_LDS(ga + kt, As + t * 8);
    GLOAD_LDS(ga + (size_t)64 * K + kt, As + 2048 + t * 8);
    GLOAD_LDS(gb + kt, Bs + t * 8);
    __syncthreads();
    bf16x8 af[4], bfr[2];
#pragma unroll
    for (int mi = 0; mi < 4; ++mi)
      af[mi] = *(const bf16x8*)(As + (wr * 64 + mi * 16 + lr) * BK + lh * 8);
#pragma unroll
    for (int ni = 0; ni < 2; ++ni)
      bfr[ni] = *(const bf16x8*)(Bs + (wc * 32 + ni * 16 + lr) * BK + lh * 8);
#pragma unroll
    for (int mi = 0; mi < 4; ++mi)
#pragma unroll
      for (int ni = 0; ni < 2; ++ni)
        acc[mi][ni] = mfma16(af[mi], bfr[ni], acc[mi][ni]);
    __syncthreads();
  }

#pragma unroll
  for (int mi = 0; mi < 4; ++mi) {
#pragma unroll
    for (int ni = 0; ni < 2; ++ni) {
      int col = n0 + wc * 32 + ni * 16 + lr;
      float bc = bias[col];
#pragma unroll
      for (int r = 0; r < 4; ++r) {
        int rowg = m0 + wr * 64 + mi * 16 + lh * 4 + r;
        Cout[(size_t)rowg * N + col] = acc[mi][ni][r] + bc;
      }
    }
  }
}

// ---------------- fused attention v9: attn8 + b128 softmax ------------------
// Same as attn8 (R16, best) except softmax does 2x b128 LDS reads/writes per
// row instead of 4x b64 (half the LDS instrs + loop overhead).
__global__ __launch_bounds__(256, 2) void attn9_kernel(const u16* __restrict__ Qh,
                                                       const u16* __restrict__ Kh,
                                                       const u16* __restrict__ Qsh,
                                                       const u16* __restrict__ Ksh,
                                                       const u16* __restrict__ Vth,
                                                       const uint32_t* __restrict__ mbits,
                                                       float* __restrict__ Pout,
                                                       u16* __restrict__ ctx) {
  __shared__ __align__(16) u16 E[32 * 1024]; // 64 KB bf16
  const int t = threadIdx.x, w = t >> 6, l = t & 63;
  const int lr = l & 15, lh = l >> 4;
  int lid = blockIdx.y * 32 + blockIdx.x;
  int xcd = lid & 7, j = lid >> 3;
  int bh = xcd * 8 + (j >> 5);
  int q0 = (j & 31) << 5;
  const int b = bh >> 4, h = bh & 15;
  const size_t hoff = (size_t)bh * Sc * HDc;

  // ---- Q fragments, both groups ----
  const u16* QpA = Qh + hoff + (size_t)(q0 + lr) * HDc + lh * 8;
  const u16* QspA = Qsh + hoff + (size_t)(q0 + lr) * HDc + lh * 8;
  bf16x8 qfA0 = *(const bf16x8*)QpA, qfA1 = *(const bf16x8*)(QpA + 32);
  bf16x8 sfA0 = *(const bf16x8*)QspA, sfA1 = *(const bf16x8*)(QspA + 32);
  bf16x8 qfB0 = *(const bf16x8*)(QpA + 16 * HDc), qfB1 = *(const bf16x8*)(QpA + 16 * HDc + 32);
  bf16x8 sfB0 = *(const bf16x8*)(QspA + 16 * HDc), sfB1 = *(const bf16x8*)(QspA + 16 * HDc + 32);

  // ---- mask words ----
  uint32_t mwA[8], mwB[8];
  {
    const uint32_t* mA = mbits + ((size_t)b * Sc + q0 + lr) * 32 + w * 8;
    *(uint4*)&mwA[0] = *(const uint4*)mA;
    *(uint4*)&mwA[4] = *(const uint4*)(mA + 4);
    const uint32_t* mB = mA + 16 * 32;
    *(uint4*)&mwB[0] = *(const uint4*)mB;
    *(uint4*)&mwB[4] = *(const uint4*)(mB + 4);
  }

  // ---- energy: wave w covers k in [w*256,(w+1)*256), depth-4 K prefetch ----
  const u16* Kbase = Kh + hoff + (size_t)((w << 8) + lr) * HDc + lh * 8;
  const u16* Ksbase = Ksh + hoff + (size_t)((w << 8) + lr) * HDc + lh * 8;

  bf16x8 ka[4], kb[4], sa[4], sb[4];
#define LOADK(slot, it) do { \
    const u16* Kp_ = Kbase + (it) * (16 * HDc); \
    const u16* Sp_ = Ksbase + (it) * (16 * HDc); \
    ka[slot] = *(const bf16x8*)Kp_;  kb[slot] = *(const bf16x8*)(Kp_ + 32); \
    sa[slot] = *(const bf16x8*)Sp_;  sb[slot] = *(const bf16x8*)(Sp_ + 32); } while (0)

  LOADK(0, 0); LOADK(1, 1); LOADK(2, 2); LOADK(3, 3);

#pragma unroll
  for (int kt = 0; kt < 16; ++kt) {
    const int s = kt & 3;
    f32x4 eA = {}, esA = {}, eB = {}, esB = {};
    eA = mfma16(ka[s], qfA0, eA);
    eA = mfma16(kb[s], qfA1, eA);
    esA = mfma16(sa[s], sfA0, esA);
    esA = mfma16(sb[s], sfA1, esA);
    eB = mfma16(ka[s], qfB0, eB);
    eB = mfma16(kb[s], qfB1, eB);
    esB = mfma16(sa[s], sfB0, esB);
    esB = mfma16(sb[s], sfB1, esB);
    if (kt + 4 < 16) LOADK(s, kt + 4);
    const int sh = ((kt & 1) << 4) + (lh << 2);
    const int kb16 = (w << 8) + (kt << 4) + (lh << 2);
    const int sphys = ((((kb16 >> 3) ^ (lr & 7)) << 3) | (kb16 & 7));
    {
      uint32_t md = mwA[kt >> 1];
      ushort4 wb;
      wb.x = f2bf(((md >> (sh + 0)) & 1u ? esA[0] : eA[0]) * 0.125f);
      wb.y = f2bf(((md >> (sh + 1)) & 1u ? esA[1] : eA[1]) * 0.125f);
      wb.z = f2bf(((md >> (sh + 2)) & 1u ? esA[2] : eA[2]) * 0.125f);
      wb.w = f2bf(((md >> (sh + 3)) & 1u ? esA[3] : eA[3]) * 0.125f);
      *(ushort4*)&E[(lr << 10) + sphys] = wb;
    }
    {
      uint32_t md = mwB[kt >> 1];
      ushort4 wb;
      wb.x = f2bf(((md >> (sh + 0)) & 1u ? esB[0] : eB[0]) * 0.125f);
      wb.y = f2bf(((md >> (sh + 1)) & 1u ? esB[1] : eB[1]) * 0.125f);
      wb.z = f2bf(((md >> (sh + 2)) & 1u ? esB[2] : eB[2]) * 0.125f);
      wb.w = f2bf(((md >> (sh + 3)) & 1u ? esB[3] : eB[3]) * 0.125f);
      *(ushort4*)&E[((lr + 16) << 10) + sphys] = wb;
    }
  }
#undef LOADK
  softbar();

  // ---- V preload: ALL frags to registers BEFORE any P store is issued ----
  const u16* Vbp = Vth + ((size_t)bh * HDc + (w << 4) + lr) * Sc + lh * 8;
  bf16x8 vr0[16], vr1[16];
#pragma unroll
  for (int it = 0; it < 16; ++it) {
    vr0[it] = *(const bf16x8*)(Vbp + it * 64);
    vr1[it] = *(const bf16x8*)(Vbp + it * 64 + 32);
  }
  __builtin_amdgcn_sched_barrier(0); // keep V loads older than the P stores

  // ---- softmax: wave w owns rows w*8..w*8+7; b128 LDS ops ----
  float* Pb = Pout + ((size_t)bh * Sc + q0) * Sc;
#pragma unroll
  for (int r8 = 0; r8 < 8; ++r8) {
    const int row = (w << 3) + r8;
    const int sw = row & 7;
    float v[2][8];
#pragma unroll
    for (int jj = 0; jj < 2; ++jj) {
      int g = ((jj << 6) + l) ^ sw;
      union { bf16x8 vv; u16 s[8]; } raw;
      raw.vv = *(const bf16x8*)&E[(row << 10) + (g << 3)];
#pragma unroll
      for (int i = 0; i < 8; ++i) v[jj][i] = bf2f(raw.s[i]);
    }
    float m = -1e30f;
#pragma unroll
    for (int jj = 0; jj < 2; ++jj)
#pragma unroll
      for (int i = 0; i < 8; ++i) m = fmaxf(m, v[jj][i]);
#pragma unroll
    for (int off = 1; off < 64; off <<= 1) m = fmaxf(m, __shfl_xor(m, off));
    float sum = 0.f;
#pragma unroll
    for (int jj = 0; jj < 2; ++jj)
#pragma unroll
      for (int i = 0; i < 8; ++i) { float tt = __expf(v[jj][i] - m); v[jj][i] = tt; sum += tt; }
#pragma unroll
    for (int off = 1; off < 64; off <<= 1) sum += __shfl_xor(sum, off);
    const float inv = 1.f / sum;
#pragma unroll
    for (int jj = 0; jj < 2; ++jj) {
      int g = ((jj << 6) + l) ^ sw;
      int k = (jj << 9) + (l << 3);
      union { bf16x8 vv; u16 s[8]; } wb;
      f32x4 p0, p1;
#pragma unroll
      for (int i = 0; i < 4; ++i) {
        p0[i] = v[jj][i] * inv;
        p1[i] = v[jj][4 + i] * inv;
        wb.s[i] = f2bf(p0[i]);
        wb.s[4 + i] = f2bf(p1[i]);
      }
      *(bf16x8*)&E[(row << 10) + (g << 3)] = wb.vv;
      *(f32x4*)(Pb + (size_t)row * Sc + k) = p0;     // 2KB/wave contiguous
      *(f32x4*)(Pb + (size_t)row * Sc + k + 4) = p1;
    }
  }

  softbar(); // LDS-only: the P stores above keep draining during PV

  // ---- PV: wave w -> d-cols [w*16,+16); zero vmem in the loop ----
  const int swp = lr & 7;
  f32x4 accA0 = {}, accA1 = {}, accB0 = {}, accB1 = {};
#pragma unroll
  for (int it = 0; it < 16; ++it) {
    int ka16 = (it << 6) + (lh << 3);
    int offL = (((ka16 >> 3) ^ swp) << 3);
    int offH = ((((ka16 + 32) >> 3) ^ swp) << 3);
    bf16x8 aA0 = *(const bf16x8*)&E[(lr << 10) + offL];
    bf16x8 aA1 = *(const bf16x8*)&E[(lr << 10) + offH];
    bf16x8 aB0 = *(const bf16x8*)&E[((lr + 16) << 10) + offL];
    bf16x8 aB1 = *(const bf16x8*)&E[((lr + 16) << 10) + offH];
    accA0 = mfma16(aA0, vr0[it], accA0);
    accA1 = mfma16(aA1, vr1[it], accA1);
    accB0 = mfma16(aB0, vr0[it], accB0);
    accB1 = mfma16(aB1, vr1[it], accB1);
  }
  f32x4 accA = accA0 + accA1;
  f32x4 accB = accB0 + accB1;
#pragma unroll
  for (int r = 0; r < 4; ++r) {
    int rowA = q0 + (lh << 2) + r;
    ctx[((size_t)b * Sc + rowA) * Hc + (h << 6) + (w << 4) + lr] = f2bf(accA[r]);
    int rowB = rowA + 16;
    ctx[((size_t)b * Sc + rowB) * Hc + (h << 6) + (w << 4) + lr] = f2bf(accB[r]);
  }
}

extern "C" void kernel_launch(void* const* d_in, const int* in_sizes, int n_in,
                              void* d_out, int out_size, void* d_ws, size_t ws_size,
                              hipStream_t stream) {
  const float* fin[5] = { (const float*)d_in[0], (const float*)d_in[1], (const float*)d_in[2],
                          (const float*)d_in[3], (const float*)d_in[4] };
  const int* mask = (const int*)d_in[5];
  const float* W[6] = { (const float*)d_in[6], (const float*)d_in[8], (const float*)d_in[10],
                        (const float*)d_in[12], (const float*)d_in[14], (const float*)d_in[16] };
  const float* bias[6] = { (const float*)d_in[7], (const float*)d_in[9], (const float*)d_in[11],
                           (const float*)d_in[13], (const float*)d_in[15], (const float*)d_in[17] };

  float* out_x = (float*)d_out;
  float* out_attn = out_x + (size_t)Bc * Sc * Hc;

  const size_t NE = (size_t)Bc * Sc * Hc; // 4M elems
  const size_t NW = (size_t)Hc * Hc;      // 1M elems
  u16* p = (u16*)d_ws;
  u16* xin[5]; for (int i = 0; i < 5; ++i) { xin[i] = p; p += NE; }
  u16* wbf[6]; for (int i = 0; i < 6; ++i) { wbf[i] = p; p += NW; }
  u16* Qh  = p; p += NE;
  u16* Kh  = p; p += NE;
  u16* Qsh = p; p += NE;
  u16* Ksh = p; p += NE;
  u16* Vth = p; p += NE;
  u16* ctx = p; p += NE;
  uint32_t* mbits = (uint32_t*)xin[0]; // reused after proj5

  {
    CV a{};
    for (int i = 0; i < 5; ++i) { a.in[i] = fin[i]; a.out[i] = xin[i]; }
    cvtN_kernel<<<dim3((int)(NE / 8 / 256), 1, 5), 256, 0, stream>>>(a, (int)(NE / 8));
  }
  {
    CV a{};
    for (int i = 0; i < 6; ++i) { a.in[i] = W[i]; a.out[i] = wbf[i]; }
    cvtN_kernel<<<dim3((int)(NW / 8 / 256), 1, 6), 256, 0, stream>>>(a, (int)(NW / 8));
  }

  P5 args;
  u16* projout[5] = { Qh, Kh, Qsh, Ksh, Vth };
  for (int i = 0; i < 5; ++i) { args.A[i] = xin[i]; args.W[i] = wbf[i]; args.b[i] = bias[i]; args.o[i] = projout[i]; }
  proj5_kernel<<<dim3(Hc / 128, Mrows / 128, 5), 256, 0, stream>>>(args);

  maskpack_kernel<<<(int)((size_t)Bc * Sc * Sc / 32 / 256), 256, 0, stream>>>(mask, mbits);

  attn9_kernel<<<dim3(Sc / 32, Bc * NHc), 256, 0, stream>>>(Qh, Kh, Qsh, Ksh, Vth, mbits, out_attn, ctx);

  gemmo_kernel<<<dim3(Hc / 64, Mrows / 128), 256, 0, stream>>>(ctx, wbf[5], bias[5], out_x);
}